// Round 8
// baseline (595.070 us; speedup 1.0000x reference)
//
#include <hip/hip_runtime.h>
#include <cstdint>
#include <cstddef>

// Mix9Net trunk via MFMA, v2: 2 blocks/CU.
// One block = one (batch, direction) slice. Activations f16 in LDS on a
// 17x16+1 packed padded grid (right-pad aliases next row's left-pad; all
// taps have |dx|<=1 so this is exact). Weights staged per K=32 slice into a
// 10 KB LDS buffer (rows padded to 80 B -> bank-uniform reads, no swizzle).
// LDS total 80,128 B -> two independent blocks per CU overlap each other's
// barriers/staging latency with MFMA.

#define HWX 15
#define NPOS 225
#define CH 128
#define NTH 512
#define AROWB 80                    // 64 B of K=32 f16 + 16 B pad
#define ABYTES (CH*AROWB)           // 10,240
#define HOFF2 ABYTES
#define GRID_SLOTS 273              // 17 rows x 16 cols + 1 tail slot
#define LDS_BYTES (ABYTES + GRID_SLOTS*256)   // 80,128
#define SAFE_PP 136                 // interior slot for discarded lanes

typedef _Float16 f16;
typedef __attribute__((ext_vector_type(8))) _Float16 f16x8;
typedef __attribute__((ext_vector_type(4))) _Float16 f16x4;
typedef __attribute__((ext_vector_type(4))) float f32x4;

// h-grid: [pp][128ch] f16, 256 B/pos, XOR-swizzle on (pp&15) => B-frag reads
// (16 consecutive pp x 4 krow) are bank-uniform (2-deep, free per m136).
__device__ __forceinline__ int hb_addr(int pp, int k){
  return HOFF2 + pp*256 + ((k*2) ^ ((pp&15)<<4));
}
// A-stage: [o][K=32] f16, 80-B row stride => (20o+4kq) mod 32 uniform banks.
__device__ __forceinline__ int a_addr(int o, int k){
  return o*AROWB + k*2;
}
__device__ __forceinline__ float silu_f(float v){ return v / (1.f + __expf(-v)); }

// Stage a [rows][K=32] f32 weight slice (row stride srcStride) into A-stage.
__device__ __forceinline__ void stage_a(char* sm, const float* __restrict__ src,
                                        int srcStride, int rows, int tid){
  const int o = tid >> 2, kq = tid & 3;
  if (o < rows){
    const float* s = src + (size_t)o*srcStride + kq*8;
    float4 fa = *(const float4*)(s);
    float4 fb = *(const float4*)(s + 4);
    f16x8 hv = { (f16)fa.x,(f16)fa.y,(f16)fa.z,(f16)fa.w,
                 (f16)fb.x,(f16)fb.y,(f16)fb.z,(f16)fb.w };
    *(f16x8*)(sm + a_addr(o, kq*8)) = hv;
  }
}

// One K=32 step: A from A-stage, B from h-grid at k-slice ks (+tap shift).
// A-frag: W[mt*16+col][krow*8+j]; B-frag: h[ks+krow*8+j][pos col]
// D: col=lane&15 (pos), row=krow*4+reg (out-ch)  [m89-verified]
template<int MT>
__device__ __forceinline__ void gemm32(const char* sm, int pb0, int pb1, int ks,
                                       int krow, int col, f32x4* acc0, f32x4* acc1){
  const int k8 = krow*8;
  f16x8 b0 = *(const f16x8*)(sm + hb_addr(pb0, ks + k8));
  f16x8 b1 = *(const f16x8*)(sm + hb_addr(pb1, ks + k8));
#pragma unroll
  for (int mt=0; mt<MT; mt++){
    f16x8 a = *(const f16x8*)(sm + a_addr(mt*16+col, k8));
    acc0[mt] = __builtin_amdgcn_mfma_f32_16x16x32_f16(a, b0, acc0[mt], 0, 0, 0);
    acc1[mt] = __builtin_amdgcn_mfma_f32_16x16x32_f16(a, b1, acc1[mt], 0, 0, 0);
  }
}

// Full K=128 pointwise pass: 4 staged K=32 steps (barrier-fenced stage buffer).
template<int MT>
__device__ __forceinline__ void pw_pass(char* sm, const float* __restrict__ w,
                                        int rows, int pb0, int pb1,
                                        int krow, int col, int tid,
                                        f32x4* acc0, f32x4* acc1){
#pragma unroll 1
  for (int ks=0; ks<CH; ks+=32){
    __syncthreads();                      // prev gemm done reading A-stage
    stage_a(sm, w + ks, CH, rows, tid);
    __syncthreads();                      // stage visible
    gemm32<MT>(sm, pb0, pb1, ks, krow, col, acc0, acc1);
  }
}

template<int MT>
__device__ __forceinline__ void zacc(f32x4* a){
#pragma unroll
  for (int m=0;m<MT;m++) a[m] = (f32x4){0.f,0.f,0.f,0.f};
}

__device__ __forceinline__ void snap8(const char* sm, f16x4* r, int pp, int krow){
#pragma unroll
  for (int mt=0;mt<8;mt++)
    r[mt] = *(const f16x4*)(sm + hb_addr(pp, mt*16 + krow*4));
}

template<int MT, bool SILU, bool RES>
__device__ __forceinline__ void wb(char* sm, const f32x4* acc,
                                   const float* __restrict__ bias,
                                   const f16x4* rsd, int pp, bool valid, int krow){
#pragma unroll
  for (int mt=0;mt<MT;mt++){
    const int ch0 = mt*16 + krow*4;
    float4 bb = *(const float4*)(bias + ch0);
    f32x4 v = acc[mt];
    v[0]+=bb.x; v[1]+=bb.y; v[2]+=bb.z; v[3]+=bb.w;
    if (SILU){
#pragma unroll
      for (int j=0;j<4;j++) v[j] = silu_f(v[j]);
    }
    if (RES){
      f16x4 r = rsd[mt];
#pragma unroll
      for (int j=0;j<4;j++) v[j] += (float)r[j];
    }
    if (valid){
      f16x4 o = { (f16)v[0],(f16)v[1],(f16)v[2],(f16)v[3] };
      *(f16x4*)(sm + hb_addr(pp, ch0)) = o;
    }
  }
}

struct P {
  const float *x, *w0, *b0, *wdc, *bdc, *wc1, *bc1, *w01, *b01, *w02, *b02, *wf, *bf;
};

__global__ __launch_bounds__(NTH, 4)
void mix9_mfma2(const P p, float* __restrict__ out)
{
  __shared__ char sm[LDS_BYTES];
  const int tid  = threadIdx.x;
  const int lane = tid & 63;
  const int wave = tid >> 6;
  const int col  = lane & 15;
  const int krow = lane >> 4;
  const int d = blockIdx.x & 3;
  const int b = blockIdx.x >> 2;

  // zero all LDS (pads must stay 0; A-stage cols 2..31 must be 0 for layer 0)
  for (int i = tid; i < LDS_BYTES/16; i += NTH)
    ((f32x4*)sm)[i] = (f32x4){0.f,0.f,0.f,0.f};
  __syncthreads();

  // stage x (2 channels) into h-grid channels 0,1
  for (int i = tid; i < 2*NPOS; i += NTH){
    const int ic = i / NPOS, n = i % NPOS;
    const int pp = (n/HWX + 1)*16 + (n%HWX + 1);
    *(f16*)(sm + hb_addr(pp, ic)) = (f16)p.x[(size_t)b*2*NPOS + i];
  }

  // per-thread N-tile constants: tile row r = wave*2 (+1); lane col = grid col
  const int r0 = wave*2, r1 = wave*2 + 1;
  const bool v0 = (col >= 1);                 // col 0 = left-pad (dummy column)
  const bool v1 = (col >= 1) && (r1 < HWX);   // wave 7 second tile is dead
  const int pb0 = v0 ? (r0+1)*16 + col : SAFE_PP;
  const int pb1 = v1 ? (r1+1)*16 + col : SAFE_PP;

  // direction taps on packed grid: {dneg, 0, -dneg}
  int dneg;
  switch (d){
    case 0:  dneg = -1;  break;    // horiz (0,-1)
    case 1:  dneg = -16; break;    // vert  (-1,0)
    case 2:  dneg = -17; break;    // diag  (-1,-1)
    default: dneg =  15; break;    // anti  (+1,-1)
  }
  const int tap[3] = { dneg, 0, -dneg };

  f32x4 acc0[8], acc1[8];
  f16x4 rsd0[8], rsd1[8];

  // ---- layer 0: h = silu(dconv0(x)); K=32 slice 0, channels 2..31 zero ----
  zacc<8>(acc0); zacc<8>(acc1);
#pragma unroll 1
  for (int k=0;k<3;k++){
    __syncthreads();
    if (tid < 256)
      *(f16*)(sm + a_addr(tid>>1, tid&1)) = (f16)p.w0[k*256 + tid];
    __syncthreads();
    gemm32<8>(sm, pb0+tap[k], pb1+tap[k], 0, krow, col, acc0, acc1);
  }
  __syncthreads();
  wb<8,true,false>(sm, acc0, p.b0, nullptr, pb0, v0, krow);
  wb<8,true,false>(sm, acc1, p.b0, nullptr, pb1, v1, krow);

  // ---- 4 directional res blocks ----
#pragma unroll 1
  for (int res=0; res<4; res++){
    const float* wd = p.wdc + (size_t)res*3*CH*CH;
    zacc<8>(acc0); zacc<8>(acc1);
#pragma unroll 1
    for (int k=0;k<3;k++){
#pragma unroll 1
      for (int ks=0; ks<CH; ks+=32){
        __syncthreads();
        stage_a(sm, wd + (size_t)k*CH*CH + ks, CH, CH, tid);
        __syncthreads();
        gemm32<8>(sm, pb0+tap[k], pb1+tap[k], ks, krow, col, acc0, acc1);
      }
    }
    __syncthreads();                       // all B-reads of h done
    snap8(sm, rsd0, pb0, krow);            // residual (own slots, pre-overwrite)
    snap8(sm, rsd1, pb1, krow);
    wb<8,true,false>(sm, acc0, p.bdc + res*CH, nullptr, pb0, v0, krow);
    wb<8,true,false>(sm, acc1, p.bdc + res*CH, nullptr, pb1, v1, krow);

    zacc<8>(acc0); zacc<8>(acc1);
    pw_pass<8>(sm, p.wc1 + (size_t)res*CH*CH, CH, pb0, pb1, krow, col, tid, acc0, acc1);
    __syncthreads();
    wb<8,true,true>(sm, acc0, p.bc1 + res*CH, rsd0, pb0, v0, krow);
    wb<8,true,true>(sm, acc1, p.bc1 + res*CH, rsd1, pb1, v1, krow);
  }

  // ---- Conv0dResBlock ----
  zacc<8>(acc0); zacc<8>(acc1);
  pw_pass<8>(sm, p.w01, CH, pb0, pb1, krow, col, tid, acc0, acc1);
  __syncthreads();
  snap8(sm, rsd0, pb0, krow);
  snap8(sm, rsd1, pb1, krow);
  wb<8,true,false>(sm, acc0, p.b01, nullptr, pb0, v0, krow);
  wb<8,true,false>(sm, acc1, p.b01, nullptr, pb1, v1, krow);

  zacc<8>(acc0); zacc<8>(acc1);
  pw_pass<8>(sm, p.w02, CH, pb0, pb1, krow, col, tid, acc0, acc1);
  __syncthreads();
  wb<8,true,true>(sm, acc0, p.b02, rsd0, pb0, v0, krow);
  wb<8,true,true>(sm, acc1, p.b02, rsd1, pb1, v1, krow);

  // ---- final 1x1: 128 -> 64, +bias, store fp32 to global ----
  zacc<4>(acc0); zacc<4>(acc1);
  pw_pass<4>(sm, p.wf, 64, pb0, pb1, krow, col, tid, acc0, acc1);

  float* ob = out + ((size_t)(b*4 + d)*64)*NPOS;
  const int nb0 = r0*HWX + (col-1);
  const int nb1 = r1*HWX + (col-1);
#pragma unroll
  for (int mt=0;mt<4;mt++){
    const int ch0 = mt*16 + krow*4;
    float4 bb = *(const float4*)(p.bf + ch0);
    const float bj[4] = {bb.x, bb.y, bb.z, bb.w};
#pragma unroll
    for (int j=0;j<4;j++){
      if (v0) ob[(size_t)(ch0+j)*NPOS + nb0] = acc0[mt][j] + bj[j];
      if (v1) ob[(size_t)(ch0+j)*NPOS + nb1] = acc1[mt][j] + bj[j];
    }
  }
}

extern "C" void kernel_launch(void* const* d_in, const int* in_sizes, int n_in,
                              void* d_out, int out_size, void* d_ws, size_t ws_size,
                              hipStream_t stream)
{
  (void)in_sizes; (void)n_in; (void)d_ws; (void)ws_size; (void)out_size;
  P p;
  p.x   = (const float*)d_in[0];
  p.w0  = (const float*)d_in[1];   // [3][128][2]
  p.b0  = (const float*)d_in[2];   // [128]
  p.wdc = (const float*)d_in[3];   // [4][3][128][128]
  p.bdc = (const float*)d_in[4];   // [4][128]
  p.wc1 = (const float*)d_in[5];   // [4][128][128]
  p.bc1 = (const float*)d_in[6];   // [4][128]
  p.w01 = (const float*)d_in[7];   // [128][128]
  p.b01 = (const float*)d_in[8];
  p.w02 = (const float*)d_in[9];
  p.b02 = (const float*)d_in[10];
  p.wf  = (const float*)d_in[11];  // [64][128]
  p.bf  = (const float*)d_in[12];  // [64]

  mix9_mfma2<<<dim3(256*4), dim3(NTH), 0, stream>>>(p, (float*)d_out);
}

// Round 9
// 518.471 us; speedup vs baseline: 1.1477x; 1.1477x over previous
//
#include <hip/hip_runtime.h>
#include <cstdint>
#include <cstddef>

// Mix9Net trunk via MFMA, v3: 256-thr blocks (4 waves), NT=4 tiles/wave,
// 2 blocks/CU without spills. Weights pre-converted to f16 in d_ws (one
// converter kernel per call); K=32 A-slices staged into an 8 KB swizzled
// LDS buffer with one-step register prefetch (T14). Activations f16 in a
// 17x16+1 packed padded grid (hardware-verified in v2).

#define HWX 15
#define NPOS 225
#define CH 128
#define NTH 256
#define ABYTES 8192                      // A-stage: [128][32] f16, XOR-swizzled
#define HOFF ABYTES
#define GRID_SLOTS 273                   // 17 rows x 16 cols + 1 tail
#define LDS_BYTES (ABYTES + GRID_SLOTS*256)   // 8192 + 69888 = 78080
#define SAFE_PP 136

// d_ws f16 element offsets (segments sequential)
#define WSE_WDC 0                        // 48 blks [128][32]: (res*3+tap)*4+ks
#define WSE_WC1 196608                   // 16 blks: res*4+ks
#define WSE_W01 262144                   // 4 blks
#define WSE_W02 278528                   // 4 blks
#define WSE_WF  294912                   // 4 blks [64][32]
#define WSE_TOTAL 303104
#define WS_NEED (WSE_TOTAL*2)

typedef _Float16 f16;
typedef __attribute__((ext_vector_type(8))) _Float16 f16x8;
typedef __attribute__((ext_vector_type(4))) _Float16 f16x4;
typedef __attribute__((ext_vector_type(4))) float f32x4;

// h-grid: [pp][128ch] f16, 256 B/slot, XOR swizzle on (pp&15) -> B-frag
// reads conflict-free (derived r6; HW-verified v2).
__device__ __forceinline__ int hb_addr(int pp, int k){
  return HOFF + pp*256 + ((k*2) ^ ((pp&15)<<4));
}
// A-stage: [o][32k] f16, 64 B/row, chunk swizzle (k>>3)^(o&3) -> both the
// staged writes and the frag reads are bank-uniform.
__device__ __forceinline__ int a_addr(int o, int k){
  return o*64 + ((((k>>3))<<4) ^ ((o&3)<<4)) + ((k&7)*2);
}
__device__ __forceinline__ float silu_f(float v){ return v / (1.f + __expf(-v)); }

struct StReg { f16x8 a, b; bool on; };

// Load one thread's 16-f16 share of a [rows][32] K-slice (WS: from f16 d_ws;
// else: from f32 weights + cvt). Issued early -> latency hides under gemm.
template<bool WS>
__device__ __forceinline__ StReg stage_load(const f16* __restrict__ wsblk,
                                            const float* __restrict__ f32p,
                                            int stride, int rows, int tid){
  StReg r;
  const int o = tid>>1, kh = tid&1;
  r.on = (o < rows);
  if (r.on){
    if (WS){
      r.a = *(const f16x8*)(wsblk + o*32 + kh*16);
      r.b = *(const f16x8*)(wsblk + o*32 + kh*16 + 8);
    } else {
      const float* s = f32p + (size_t)o*stride + kh*16;
      float4 x0 = *(const float4*)(s);
      float4 x1 = *(const float4*)(s+4);
      float4 x2 = *(const float4*)(s+8);
      float4 x3 = *(const float4*)(s+12);
      r.a = (f16x8){(f16)x0.x,(f16)x0.y,(f16)x0.z,(f16)x0.w,
                    (f16)x1.x,(f16)x1.y,(f16)x1.z,(f16)x1.w};
      r.b = (f16x8){(f16)x2.x,(f16)x2.y,(f16)x2.z,(f16)x2.w,
                    (f16)x3.x,(f16)x3.y,(f16)x3.z,(f16)x3.w};
    }
  }
  return r;
}

__device__ __forceinline__ void stage_write(char* sm, StReg r, int tid){
  const int o = tid>>1, kh = tid&1;
  if (r.on){
    *(f16x8*)(sm + a_addr(o, kh*16))   = r.a;
    *(f16x8*)(sm + a_addr(o, kh*16+8)) = r.b;
  }
}

// One K=32 step. A-frag: W[mt*16+col][krow*8+j] (stage-local k).
// B-frag: h[ks+krow*8+j][pos]. D: col=lane&15 (pos), row=krow*4+reg (ch).
template<int MT>
__device__ __forceinline__ void gemm32(const char* sm, const int* pbs, int ks,
                                       int krow, int col, f32x4 acc[4][8]){
  const int kb = ks + krow*8;
  const int ka = krow*8;
  f16x8 b0 = *(const f16x8*)(sm + hb_addr(pbs[0], kb));
  f16x8 b1 = *(const f16x8*)(sm + hb_addr(pbs[1], kb));
  f16x8 b2 = *(const f16x8*)(sm + hb_addr(pbs[2], kb));
  f16x8 b3 = *(const f16x8*)(sm + hb_addr(pbs[3], kb));
#pragma unroll
  for (int mt=0; mt<MT; mt++){
    f16x8 a = *(const f16x8*)(sm + a_addr(mt*16+col, ka));
    acc[0][mt] = __builtin_amdgcn_mfma_f32_16x16x32_f16(a, b0, acc[0][mt], 0,0,0);
    acc[1][mt] = __builtin_amdgcn_mfma_f32_16x16x32_f16(a, b1, acc[1][mt], 0,0,0);
    acc[2][mt] = __builtin_amdgcn_mfma_f32_16x16x32_f16(a, b2, acc[2][mt], 0,0,0);
    acc[3][mt] = __builtin_amdgcn_mfma_f32_16x16x32_f16(a, b3, acc[3][mt], 0,0,0);
  }
}

// Full K=128 pass: 4 staged K=32 steps with 1-step prefetch.
template<int MT, bool WS>
__device__ __forceinline__ void pw_pass(char* sm, const f16* __restrict__ wsblk,
                                        const float* __restrict__ f32p,
                                        int stride, int rows, const int* pbs,
                                        int krow, int col, int tid, f32x4 acc[4][8]){
  StReg cur = stage_load<WS>(wsblk, f32p, stride, rows, tid);
#pragma unroll 1
  for (int ks=0; ks<CH; ks+=32){
    __syncthreads();                       // prev gemm done with A-stage
    stage_write(sm, cur, tid);
    if (ks+32 < CH)
      cur = stage_load<WS>(wsblk + (ks/32+1)*rows*32, f32p + ks + 32, stride, rows, tid);
    __syncthreads();                       // stage visible
    gemm32<MT>(sm, pbs, ks, krow, col, acc);
  }
}

__device__ __forceinline__ void zacc_all(f32x4 acc[4][8]){
#pragma unroll
  for (int t=0;t<4;t++)
#pragma unroll
    for (int m=0;m<8;m++) acc[t][m] = (f32x4){0.f,0.f,0.f,0.f};
}

__device__ __forceinline__ void snap4x8(const char* sm, f16x4 r[4][8],
                                        const int* pbs, int krow){
#pragma unroll
  for (int t=0;t<4;t++)
#pragma unroll
    for (int mt=0;mt<8;mt++)
      r[t][mt] = *(const f16x4*)(sm + hb_addr(pbs[t], mt*16 + krow*4));
}

template<int MT, bool SILU, bool RES>
__device__ __forceinline__ void wb4(char* sm, f32x4 acc[4][8],
                                    const float* __restrict__ bias,
                                    f16x4 rsd[4][8], const int* pbs,
                                    const bool* val, int krow){
#pragma unroll
  for (int mt=0;mt<MT;mt++){
    const int ch0 = mt*16 + krow*4;
    float4 bb = *(const float4*)(bias + ch0);
    const float bj[4] = {bb.x, bb.y, bb.z, bb.w};
#pragma unroll
    for (int t=0;t<4;t++){
      f32x4 v = acc[t][mt];
#pragma unroll
      for (int j=0;j<4;j++) v[j] += bj[j];
      if (SILU){
#pragma unroll
        for (int j=0;j<4;j++) v[j] = silu_f(v[j]);
      }
      if (RES){
        f16x4 r = rsd[t][mt];
#pragma unroll
        for (int j=0;j<4;j++) v[j] += (float)r[j];
      }
      if (val[t]){
        f16x4 o = { (f16)v[0],(f16)v[1],(f16)v[2],(f16)v[3] };
        *(f16x4*)(sm + hb_addr(pbs[t], ch0)) = o;
      }
    }
  }
}

struct P {
  const float *x, *w0, *b0, *wdc, *bdc, *wc1, *bc1, *w01, *b01, *w02, *b02, *wf, *bf;
};

template<bool WS>
__global__ __launch_bounds__(NTH, 2)
void mix9_v3(const P p, const f16* __restrict__ wsf, float* __restrict__ out)
{
  __shared__ char sm[LDS_BYTES];
  const int tid  = threadIdx.x;
  const int lane = tid & 63;
  const int wave = tid >> 6;
  const int col  = lane & 15;
  const int krow = lane >> 4;
  const int d = blockIdx.x & 3;
  const int b = blockIdx.x >> 2;

  for (int i = tid; i < LDS_BYTES/16; i += NTH)
    ((f32x4*)sm)[i] = (f32x4){0.f,0.f,0.f,0.f};
  __syncthreads();

  for (int i = tid; i < 2*NPOS; i += NTH){
    const int ic = i/NPOS, n = i%NPOS;
    const int pp = (n/HWX + 1)*16 + (n%HWX + 1);
    *(f16*)(sm + hb_addr(pp, ic)) = (f16)p.x[(size_t)b*2*NPOS + i];
  }

  int pbs[4]; bool val[4];
#pragma unroll
  for (int t=0;t<4;t++){
    const int r = wave*4 + t;                 // 0..15 (15 = dead tile)
    val[t] = (col >= 1) && (r < HWX);
    pbs[t] = val[t] ? (r+1)*16 + col : SAFE_PP;
  }
  int dneg;
  switch (d){
    case 0:  dneg = -1;  break;   // horiz (0,-1)
    case 1:  dneg = -16; break;   // vert  (-1,0)
    case 2:  dneg = -17; break;   // diag  (-1,-1)
    default: dneg =  15; break;   // anti  (+1,-1)
  }

  f32x4 acc[4][8];
  f16x4 rsd[4][8];

  // ---- layer 0: h = silu(dconv0(x)); A-stage k>=2 stays zero-initialized ----
  zacc_all(acc);
#pragma unroll 1
  for (int k=0;k<3;k++){
    const int sh = (k==0) ? dneg : (k==1) ? 0 : -dneg;
    int pbt[4];
#pragma unroll
    for (int t=0;t<4;t++) pbt[t] = pbs[t] + sh;
    __syncthreads();
    *(f16*)(sm + a_addr(tid>>1, tid&1)) = (f16)p.w0[k*256 + tid];
    __syncthreads();
    gemm32<8>(sm, pbt, 0, krow, col, acc);
  }
  __syncthreads();
  wb4<8,true,false>(sm, acc, p.b0, nullptr, pbs, val, krow);

  // ---- 4 directional res blocks ----
#pragma unroll 1
  for (int res=0; res<4; res++){
    zacc_all(acc);
#pragma unroll 1
    for (int k=0;k<3;k++){
      const int sh = (k==0) ? dneg : (k==1) ? 0 : -dneg;
      int pbt[4];
#pragma unroll
      for (int t=0;t<4;t++) pbt[t] = pbs[t] + sh;
      const f16* blk = wsf + WSE_WDC + (size_t)(res*3 + k)*4*4096;
      const float* fp = p.wdc + (size_t)(res*3 + k)*CH*CH;
      pw_pass<8,WS>(sm, blk, fp, CH, CH, pbt, krow, col, tid, acc);
    }
    __syncthreads();                          // all B-reads of h done
    snap4x8(sm, rsd, pbs, krow);              // residual = pre-dconv h (own slots)
    wb4<8,true,false>(sm, acc, p.bdc + res*CH, nullptr, pbs, val, krow);

    zacc_all(acc);
    pw_pass<8,WS>(sm, wsf + WSE_WC1 + (size_t)res*4*4096,
                  p.wc1 + (size_t)res*CH*CH, CH, CH, pbs, krow, col, tid, acc);
    __syncthreads();
    wb4<8,true,true>(sm, acc, p.bc1 + res*CH, rsd, pbs, val, krow);
  }

  // ---- Conv0dResBlock ----
  zacc_all(acc);
  pw_pass<8,WS>(sm, wsf + WSE_W01, p.w01, CH, CH, pbs, krow, col, tid, acc);
  __syncthreads();
  snap4x8(sm, rsd, pbs, krow);
  wb4<8,true,false>(sm, acc, p.b01, nullptr, pbs, val, krow);

  zacc_all(acc);
  pw_pass<8,WS>(sm, wsf + WSE_W02, p.w02, CH, CH, pbs, krow, col, tid, acc);
  __syncthreads();
  wb4<8,true,true>(sm, acc, p.b02, rsd, pbs, val, krow);

  // ---- final 1x1: 128 -> 64 (+bias), store fp32 ----
  zacc_all(acc);
  pw_pass<4,WS>(sm, wsf + WSE_WF, p.wf, CH, 64, pbs, krow, col, tid, acc);

  float* ob = out + ((size_t)(b*4 + d)*64)*NPOS;
#pragma unroll
  for (int t=0;t<4;t++){
    const int r = wave*4 + t;
    const int n = r*HWX + (col-1);
#pragma unroll
    for (int mt=0;mt<4;mt++){
      const int ch0 = mt*16 + krow*4;
      float4 bb = *(const float4*)(p.bf + ch0);
      const float bj[4] = {bb.x, bb.y, bb.z, bb.w};
#pragma unroll
      for (int j=0;j<4;j++)
        if (val[t]) ob[(size_t)(ch0+j)*NPOS + n] = acc[t][mt][j] + bj[j];
    }
  }
}

// Converter: f32 weights -> f16 d_ws in [block][o][k32] layout (plain rows;
// the swizzle is applied at LDS-write time in the main kernel).
__global__ void cvt_ws(const P p, f16* __restrict__ ws)
{
  const int idx = blockIdx.x*NTH + threadIdx.x;
  if (idx >= WSE_TOTAL) return;
  float v;
  if (idx < WSE_WC1){
    int blk = idx >> 12, rem = idx & 4095;
    int o = rem >> 5, k = rem & 31;
    int ks = blk & 3, tapres = blk >> 2;          // res*3+tap
    v = p.wdc[((size_t)tapres*CH + o)*CH + ks*32 + k];
  } else if (idx < WSE_W01){
    int j = idx - WSE_WC1;
    int blk = j >> 12, rem = j & 4095;
    int o = rem >> 5, k = rem & 31;
    int ks = blk & 3, res = blk >> 2;
    v = p.wc1[((size_t)res*CH + o)*CH + ks*32 + k];
  } else if (idx < WSE_W02){
    int j = idx - WSE_W01;
    int ks = j >> 12, rem = j & 4095;
    int o = rem >> 5, k = rem & 31;
    v = p.w01[(size_t)o*CH + ks*32 + k];
  } else if (idx < WSE_WF){
    int j = idx - WSE_W02;
    int ks = j >> 12, rem = j & 4095;
    int o = rem >> 5, k = rem & 31;
    v = p.w02[(size_t)o*CH + ks*32 + k];
  } else {
    int j = idx - WSE_WF;
    int ks = j >> 11, rem = j & 2047;
    int o = rem >> 5, k = rem & 31;
    v = p.wf[(size_t)o*CH + ks*32 + k];
  }
  ws[idx] = (f16)v;
}

extern "C" void kernel_launch(void* const* d_in, const int* in_sizes, int n_in,
                              void* d_out, int out_size, void* d_ws, size_t ws_size,
                              hipStream_t stream)
{
  (void)in_sizes; (void)n_in; (void)out_size;
  P p;
  p.x   = (const float*)d_in[0];
  p.w0  = (const float*)d_in[1];   // [3][128][2]
  p.b0  = (const float*)d_in[2];
  p.wdc = (const float*)d_in[3];   // [4][3][128][128]
  p.bdc = (const float*)d_in[4];
  p.wc1 = (const float*)d_in[5];   // [4][128][128]
  p.bc1 = (const float*)d_in[6];
  p.w01 = (const float*)d_in[7];
  p.b01 = (const float*)d_in[8];
  p.w02 = (const float*)d_in[9];
  p.b02 = (const float*)d_in[10];
  p.wf  = (const float*)d_in[11];  // [64][128]
  p.bf  = (const float*)d_in[12];

  float* out = (float*)d_out;
  const bool ws_ok = (d_ws != nullptr) && (ws_size >= (size_t)WS_NEED);

  if (ws_ok){
    f16* ws = (f16*)d_ws;
    cvt_ws<<<dim3((WSE_TOTAL + NTH - 1)/NTH), dim3(NTH), 0, stream>>>(p, ws);
    mix9_v3<true><<<dim3(256*4), dim3(NTH), 0, stream>>>(p, ws, out);
  } else {
    mix9_v3<false><<<dim3(256*4), dim3(NTH), 0, stream>>>(p, nullptr, out);
  }
}